// Round 18
// baseline (14.861 us; speedup 1.0000x reference)
//
#include <hip/hip_runtime.h>

#define T_LEN 1024
#define B_LEN 64
#define CLEN 32          // work steps per chunk; each block carries TWO chunks
#define BURN 8           // measured safety floor: burn=8 -> absmax 0.0; burn=0 -> 5632
#define NBLK (B_LEN * 16)
#define NPART (2 * NBLK)

typedef float v2f __attribute__((ext_vector_type(2)));

// One DPP-add level: x += dpp_move(x, CTRL), out-of-bounds lanes read 0.
template <int CTRL>
__device__ __forceinline__ float dpp_add(float x)
{
    int y = __builtin_amdgcn_update_dpp(0, __builtin_bit_cast(int, x), CTRL, 0xf, 0xf, true);
    return x + __builtin_bit_cast(float, y);
}
__device__ __forceinline__ v2f fma2(v2f a, v2f b, v2f c) { return __builtin_elementwise_fma(a, b, c); }
__device__ __forceinline__ float rl63(float x)
{
    return __builtin_bit_cast(float, __builtin_amdgcn_readlane(__builtin_bit_cast(int, x), 63));
}

// Dual-chunk time-chunked scaled HMM forward. Block j of row b carries TWO
// independent chunks: A = [64j, 64j+32), B = [64j+32, 64j+64), each with the
// full 512-state filter (8 states/lane/chunk as 4 v2f). The two Z-recursions
// are textually interleaved so chunk B's VALU/exp work fills chunk A's DPP
// reduce latency (~80cy/step exposed at 1 wave/SIMD) and vice versa --
// real work as the latency filler instead of a second wave (2 waves/SIMD
// serialize, R10 vs R11) or extra restructuring ops (lag-2, R6).
// Non-initial chunks burn 8 steps from a uniform start (measured floor);
// block j=0's A-chunk starts exactly from pi at t=0 and runs 8 dead tail
// steps with its accumulators snapshotted at group-4 entry.
// 1024 blocks = 1 wave/SIMD. Two partials per block; 1-wave reduce kernel.
__global__ __launch_bounds__(64) void hmm_fwd_kernel(const float* __restrict__ obvs,
                                                     const float* __restrict__ mu,
                                                     const float* __restrict__ ln_pi,
                                                     float* __restrict__ part)
{
    const int bid  = blockIdx.x;
    const int b    = bid >> 4;          // batch row
    const int j    = bid & 15;          // dual-chunk index
    const int lane = threadIdx.x;

    const bool exactA  = (j == 0);                 // chunk A starts at t=0 from pi
    const int  t0A     = exactA ? 0 : (64 * j - BURN);
    const int  t0B     = 64 * j + 32 - BURN;       // always > 0
    const int  g_resetA = exactA ? 0 : 1;          // 0 = never (loop starts at g=1)

    __shared__ __align__(16) float s_obs[2][64];
    const float* orow = obvs + (size_t)b * T_LEN;
    {
        const int tA = t0A + lane;
        s_obs[0][lane] = (lane < 56 && tA < T_LEN) ? orow[tA] : 0.0f;
        const int tB = t0B + lane;
        s_obs[1][lane] = (lane < 56 && tB < T_LEN) ? orow[tB] : 0.0f;
    }
    __syncthreads();

    const float C1    = -0.7213475204444817f;   // -0.5 * log2(e)
    const float C2    = -1.3257480647361593f;   // -0.5 * log2(2*pi)
    const float LOG2E =  1.4426950408889634f;
    const float KE    =  0.1f / 512.0f;         // eps / S
    const float LN2   =  0.6931471805599453f;

    // per-state constants (shared by both chunks)
    v2f mp2[4], mq2[4], lp2[4];
    {
        const float4 mua = reinterpret_cast<const float4*>(mu)[2 * lane];
        const float4 mub = reinterpret_cast<const float4*>(mu)[2 * lane + 1];
        const float4 pia = reinterpret_cast<const float4*>(ln_pi)[2 * lane];
        const float4 pib = reinterpret_cast<const float4*>(ln_pi)[2 * lane + 1];
        const float m[8]  = {mua.x, mua.y, mua.z, mua.w, mub.x, mub.y, mub.z, mub.w};
        const float lp[8] = {pia.x, pia.y, pia.z, pia.w, pib.x, pib.y, pib.z, pib.w};
#pragma unroll
        for (int i = 0; i < 4; ++i) {
            mp2[i] = (v2f){-2.0f * C1 * m[2 * i], -2.0f * C1 * m[2 * i + 1]};
            mq2[i] = (v2f){fmaf(C1 * m[2 * i], m[2 * i], C2),
                           fmaf(C1 * m[2 * i + 1], m[2 * i + 1], C2)};
            lp2[i] = exactA ? (v2f){lp[2 * i] * LOG2E, lp[2 * i + 1] * LOG2E}
                            : (v2f){0.0f, 0.0f};
        }
    }

    v2f a2A[4], e2A[4], a2B[4], e2B[4];
    float ZA, ZB;
    v2f c9A, kzA, c9B, kzB;
    float accA = 0.0f, accB = 0.0f;
    v2f osqA = (v2f){0.0f, 0.0f}, osqB = (v2f){0.0f, 0.0f};
    float accA_sav = 0.0f;
    v2f osqA_sav = (v2f){0.0f, 0.0f};

    // one dual-step: advance both chunks; the two DPP chains interleave with
    // each other's alpha-update and next-step emission prep.
    auto stepd = [&](float onA, float onB, bool renorm) {
#pragma unroll
        for (int i = 0; i < 4; ++i) a2A[i] = e2A[i] * fma2(a2A[i], c9A, kzA);
        v2f sA = (a2A[0] + a2A[1]) + (a2A[2] + a2A[3]);
        float lA = sA[0] + sA[1];
        lA = dpp_add<0x111>(lA);
#pragma unroll
        for (int i = 0; i < 4; ++i) a2B[i] = e2B[i] * fma2(a2B[i], c9B, kzB);
        lA = dpp_add<0x112>(lA);
        v2f sB = (a2B[0] + a2B[1]) + (a2B[2] + a2B[3]);
        float lB = sB[0] + sB[1];
        lA = dpp_add<0x114>(lA);
        lB = dpp_add<0x111>(lB);
        const v2f oA = (v2f){onA, onA};
        v2f qa0 = fma2(mp2[0], oA, mq2[0]);
        v2f qa1 = fma2(mp2[1], oA, mq2[1]);
        v2f qa2 = fma2(mp2[2], oA, mq2[2]);
        v2f qa3 = fma2(mp2[3], oA, mq2[3]);
        lA = dpp_add<0x118>(lA);
        lB = dpp_add<0x112>(lB);
        float ea0 = __builtin_amdgcn_exp2f(qa0[0]);
        float ea1 = __builtin_amdgcn_exp2f(qa0[1]);
        float ea2 = __builtin_amdgcn_exp2f(qa1[0]);
        float ea3 = __builtin_amdgcn_exp2f(qa1[1]);
        lA = dpp_add<0x142>(lA);
        lB = dpp_add<0x114>(lB);
        float ea4 = __builtin_amdgcn_exp2f(qa2[0]);
        float ea5 = __builtin_amdgcn_exp2f(qa2[1]);
        float ea6 = __builtin_amdgcn_exp2f(qa3[0]);
        float ea7 = __builtin_amdgcn_exp2f(qa3[1]);
        lA = dpp_add<0x143>(lA);
        lB = dpp_add<0x118>(lB);
        const v2f oB = (v2f){onB, onB};
        v2f qb0 = fma2(mp2[0], oB, mq2[0]);
        v2f qb1 = fma2(mp2[1], oB, mq2[1]);
        v2f qb2 = fma2(mp2[2], oB, mq2[2]);
        v2f qb3 = fma2(mp2[3], oB, mq2[3]);
        ZA = rl63(lA);
        lB = dpp_add<0x142>(lB);
        float eb0 = __builtin_amdgcn_exp2f(qb0[0]);
        float eb1 = __builtin_amdgcn_exp2f(qb0[1]);
        float eb2 = __builtin_amdgcn_exp2f(qb1[0]);
        float eb3 = __builtin_amdgcn_exp2f(qb1[1]);
        lB = dpp_add<0x143>(lB);
        if (renorm) {
            accA += __builtin_amdgcn_logf(ZA);
            const float rA = __builtin_amdgcn_rcpf(ZA);
            const float cA = 0.9f * rA;
            c9A = (v2f){cA, cA};
            kzA = (v2f){KE, KE};
        } else {
            const float kA = KE * ZA;
            c9A = (v2f){0.9f, 0.9f};
            kzA = (v2f){kA, kA};
        }
        float eb4 = __builtin_amdgcn_exp2f(qb2[0]);
        float eb5 = __builtin_amdgcn_exp2f(qb2[1]);
        float eb6 = __builtin_amdgcn_exp2f(qb3[0]);
        float eb7 = __builtin_amdgcn_exp2f(qb3[1]);
        ZB = rl63(lB);
        if (renorm) {
            accB += __builtin_amdgcn_logf(ZB);
            const float rB = __builtin_amdgcn_rcpf(ZB);
            const float cB = 0.9f * rB;
            c9B = (v2f){cB, cB};
            kzB = (v2f){KE, KE};
        } else {
            const float kB = KE * ZB;
            c9B = (v2f){0.9f, 0.9f};
            kzB = (v2f){kB, kB};
        }
        e2A[0] = (v2f){ea0, ea1}; e2A[1] = (v2f){ea2, ea3};
        e2A[2] = (v2f){ea4, ea5}; e2A[3] = (v2f){ea6, ea7};
        e2B[0] = (v2f){eb0, eb1}; e2B[1] = (v2f){eb2, eb3};
        e2B[2] = (v2f){eb4, eb5}; e2B[3] = (v2f){eb6, eb7};
    };

    float ocA[8], ocB[8];
#pragma unroll
    for (int k = 0; k < 8; ++k) { ocA[k] = s_obs[0][k]; ocB[k] = s_obs[1][k]; }

    {   // group-0 init at local step 0 (A: pi if exactA else uniform; B: uniform)
        const v2f oA0 = (v2f){ocA[0], ocA[0]};
        const v2f oB0 = (v2f){ocB[0], ocB[0]};
#pragma unroll
        for (int i = 0; i < 4; ++i) {
            v2f qA = fma2(mp2[i], oA0, mq2[i]) + lp2[i];    // lp2 is 0 when !exactA
            a2A[i] = (v2f){__builtin_amdgcn_exp2f(qA[0]), __builtin_amdgcn_exp2f(qA[1])};
            v2f qB = fma2(mp2[i], oB0, mq2[i]);
            a2B[i] = (v2f){__builtin_amdgcn_exp2f(qB[0]), __builtin_amdgcn_exp2f(qB[1])};
        }
        v2f sA = (a2A[0] + a2A[1]) + (a2A[2] + a2A[3]);
        v2f sB = (a2B[0] + a2B[1]) + (a2B[2] + a2B[3]);
        float lA = sA[0] + sA[1];
        float lB = sB[0] + sB[1];
        lA = dpp_add<0x111>(lA); lB = dpp_add<0x111>(lB);
        lA = dpp_add<0x112>(lA); lB = dpp_add<0x112>(lB);
        lA = dpp_add<0x114>(lA); lB = dpp_add<0x114>(lB);
        lA = dpp_add<0x118>(lA); lB = dpp_add<0x118>(lB);
        lA = dpp_add<0x142>(lA); lB = dpp_add<0x142>(lB);
        lA = dpp_add<0x143>(lA); lB = dpp_add<0x143>(lB);
        ZA = rl63(lA);
        ZB = rl63(lB);
        c9A = (v2f){0.9f, 0.9f}; kzA = (v2f){KE * ZA, KE * ZA};
        c9B = (v2f){0.9f, 0.9f}; kzB = (v2f){KE * ZB, KE * ZB};
        const v2f oA1 = (v2f){ocA[1], ocA[1]};
        const v2f oB1 = (v2f){ocB[1], ocB[1]};
#pragma unroll
        for (int i = 0; i < 4; ++i) {
            v2f qA = fma2(mp2[i], oA1, mq2[i]);
            e2A[i] = (v2f){__builtin_amdgcn_exp2f(qA[0]), __builtin_amdgcn_exp2f(qA[1])};
            v2f qB = fma2(mp2[i], oB1, mq2[i]);
            e2B[i] = (v2f){__builtin_amdgcn_exp2f(qB[0]), __builtin_amdgcn_exp2f(qB[1])};
        }
    }
#pragma unroll
    for (int k = 0; k < 8; k += 2) {     // osq over group 0
        osqA = fma2((v2f){ocA[k], ocA[k + 1]}, (v2f){ocA[k], ocA[k + 1]}, osqA);
        osqB = fma2((v2f){ocB[k], ocB[k + 1]}, (v2f){ocB[k], ocB[k + 1]}, osqB);
    }

    // group 0 steps 1..7 (renorm at local 7)
#pragma unroll
    for (int k = 1; k < 7; ++k) stepd(ocA[k + 1], ocB[k + 1], false);
    stepd(s_obs[0][8], s_obs[1][8], true);
#pragma unroll
    for (int k = 0; k < 8; ++k) { ocA[k] = s_obs[0][8 + k]; ocB[k] = s_obs[1][8 + k]; }

    // groups g = 1..4
#pragma unroll 1
    for (int g = 1; g < 5; ++g) {
        const float4 na0 = *reinterpret_cast<const float4*>(&s_obs[0][8 * g + 8]);
        const float4 na1 = *reinterpret_cast<const float4*>(&s_obs[0][8 * g + 12]);
        const float4 nb0 = *reinterpret_cast<const float4*>(&s_obs[1][8 * g + 8]);
        const float4 nb1 = *reinterpret_cast<const float4*>(&s_obs[1][8 * g + 12]);
        if (exactA && g == 4) {           // A's work [0,32) complete; tail is dead
            accA_sav = accA;
            osqA_sav = osqA;
        }
        if (g == 1) {                     // discard burn-in accumulators
            if (g_resetA == 1) { accA = 0.0f; osqA = (v2f){0.0f, 0.0f}; }
            accB = 0.0f; osqB = (v2f){0.0f, 0.0f};
        }
#pragma unroll
        for (int k = 0; k < 8; k += 2) {
            osqA = fma2((v2f){ocA[k], ocA[k + 1]}, (v2f){ocA[k], ocA[k + 1]}, osqA);
            osqB = fma2((v2f){ocB[k], ocB[k + 1]}, (v2f){ocB[k], ocB[k + 1]}, osqB);
        }
#pragma unroll
        for (int k = 0; k < 7; ++k) stepd(ocA[k + 1], ocB[k + 1], false);
        stepd(na0.x, nb0.x, true);
        ocA[0] = na0.x; ocA[1] = na0.y; ocA[2] = na0.z; ocA[3] = na0.w;
        ocA[4] = na1.x; ocA[5] = na1.y; ocA[6] = na1.z; ocA[7] = na1.w;
        ocB[0] = nb0.x; ocB[1] = nb0.y; ocB[2] = nb0.z; ocB[3] = nb0.w;
        ocB[4] = nb1.x; ocB[5] = nb1.y; ocB[6] = nb1.z; ocB[7] = nb1.w;
    }

    if (lane == 0) {
        const float accA_use = exactA ? accA_sav : accA;
        const v2f   osqA_use = exactA ? osqA_sav : osqA;
        part[2 * bid]     = LN2 * (accA_use + C1 * (osqA_use[0] + osqA_use[1]));
        part[2 * bid + 1] = LN2 * (accB + C1 * (osqB[0] + osqB[1]));
    }
}

// Deterministic tree-reduce of the NPART partials; plain store to out[0].
__global__ __launch_bounds__(64) void hmm_reduce_kernel(const float* __restrict__ part,
                                                        float* __restrict__ out)
{
    const int lane = threadIdx.x;
    float s = 0.0f;
#pragma unroll
    for (int k = 0; k < NPART / 64 / 4; ++k) {       // float4 strided over one wave
        const float4 v = reinterpret_cast<const float4*>(part)[lane + 64 * k];
        s += (v.x + v.y) + (v.z + v.w);
    }
    s = dpp_add<0x111>(s); s = dpp_add<0x112>(s); s = dpp_add<0x114>(s);
    s = dpp_add<0x118>(s); s = dpp_add<0x142>(s); s = dpp_add<0x143>(s);
    const float tot = rl63(s);
    if (lane == 0) out[0] = tot;
}

extern "C" void kernel_launch(void* const* d_in, const int* in_sizes, int n_in,
                              void* d_out, int out_size, void* d_ws, size_t ws_size,
                              hipStream_t stream)
{
    const float* obvs  = (const float*)d_in[0];
    const float* mu    = (const float*)d_in[1];
    const float* ln_pi = (const float*)d_in[2];
    float* out  = (float*)d_out;
    float* part = (float*)d_ws;

    hmm_fwd_kernel<<<NBLK, 64, 0, stream>>>(obvs, mu, ln_pi, part);
    hmm_reduce_kernel<<<1, 64, 0, stream>>>(part, out);
}

// Round 19
// 14.543 us; speedup vs baseline: 1.0219x; 1.0219x over previous
//
#include <hip/hip_runtime.h>

#define T_LEN 1024
#define B_LEN 64
#define NCHUNK 16
#define CLEN 64          // work steps per chunk
#define BURN_MAX 8       // burn-in steps. MEASURED SAFETY FLOOR: burn=8 -> absmax 0.0,
                         // burn=0 -> absmax 5632 (~5.9 lnZ bias/boundary). Do not reduce.
#define NBLK (B_LEN * NCHUNK)

typedef float v2f __attribute__((ext_vector_type(2)));

// One DPP-add level: x += dpp_move(x, CTRL), out-of-bounds lanes read 0.
template <int CTRL>
__device__ __forceinline__ float dpp_add(float x)
{
    int y = __builtin_amdgcn_update_dpp(0, __builtin_bit_cast(int, x), CTRL, 0xf, 0xf, true);
    return x + __builtin_bit_cast(float, y);
}
__device__ __forceinline__ v2f fma2(v2f a, v2f b, v2f c) { return __builtin_elementwise_fma(a, b, c); }
__device__ __forceinline__ float rl63(float x)
{
    return __builtin_bit_cast(float, __builtin_amdgcn_readlane(__builtin_bit_cast(int, x), 63));
}

// Time-chunked scaled HMM forward -- measured-optimal configuration
// (reproduced at 14.35 / 14.47 us; R1 baseline was 330 us).
//
// Decomposition: A = 0.9 I + (0.1/S) J lets the O(S^2) log-matvec collapse to
// alpha' = E o (0.9 alpha + (eps/S) Z), Z = sum(alpha). Work in the scaled
// linear domain; renorm every 8 steps with 1/Z folded into the NEXT step's
// coefficients; state-uniform exp2(C1*o^2) emission factor dropped and
// restored at the end via C1*sum(o^2).
//
// Parallelization: block = (row b, chunk c); work region t in [64c, 64c+64);
// non-initial chunks burn in 8 steps from a uniform start (likelihood-driven
// contraction kills the boundary perturbation by >6 orders in 8 steps:
// burn=8 absmax 0.0, burn=0 absmax 5632). 1024 blocks = 1 wave/SIMD.
//
// Measured-negative alternatives (do not revisit): coop grid.sync ~+60us;
// in-graph memset+atomicAdd ~+21us; obs via in-loop global loads +0.8us;
// 2 waves/SIMD serialize (~1.85x per-step); lag-2 scalar recursion +78cy/step;
// dual-chunk-per-wave interleave null (issue/trans pipe saturated: per-step
// ~200cy = 8 quarter-rate v_exp_f32 + ~55cy VALU issue; DPP chain hidden).
__global__ __launch_bounds__(64) void hmm_fwd_kernel(const float* __restrict__ obvs,
                                                     const float* __restrict__ mu,
                                                     const float* __restrict__ ln_pi,
                                                     float* __restrict__ part)
{
    const int bid  = blockIdx.x;
    const int b    = bid >> 4;          // batch row
    const int c    = bid & 15;          // time chunk
    const int lane = threadIdx.x;

    const int burn    = (CLEN * c < BURN_MAX) ? CLEN * c : BURN_MAX;
    const int t0      = CLEN * c - burn;      // first step this block simulates
    const int ng      = (burn + CLEN) >> 3;   // groups of 8 steps (incl. init group)
    const int g_reset = burn >> 3;            // discard accumulators entering this group
    const int wlen    = 8 * ng + 8;           // obs window incl. prefetch pad

    __shared__ __align__(16) float s_obs[BURN_MAX + CLEN + 16];
    const float* orow = obvs + (size_t)b * T_LEN;
#pragma unroll
    for (int k = 0; k < 2; ++k) {
        const int idx = lane + 64 * k;
        float v = 0.0f;
        if (idx < wlen && (t0 + idx) < T_LEN) v = orow[t0 + idx];
        if (idx < (int)(sizeof(s_obs) / sizeof(float))) s_obs[idx] = v;
    }
    __syncthreads();

    const float C1    = -0.7213475204444817f;   // -0.5 * log2(e)
    const float C2    = -1.3257480647361593f;   // -0.5 * log2(2*pi)
    const float LOG2E =  1.4426950408889634f;
    const float KE    =  0.1f / 512.0f;         // eps / S
    const float LN2   =  0.6931471805599453f;

    // per-state constants: reduced emission exponent q~ = mp*o + mq
    v2f mp2[4], mq2[4], lp2[4];
    {
        const float4 mua = reinterpret_cast<const float4*>(mu)[2 * lane];
        const float4 mub = reinterpret_cast<const float4*>(mu)[2 * lane + 1];
        const float4 pia = reinterpret_cast<const float4*>(ln_pi)[2 * lane];
        const float4 pib = reinterpret_cast<const float4*>(ln_pi)[2 * lane + 1];
        const float m[8]  = {mua.x, mua.y, mua.z, mua.w, mub.x, mub.y, mub.z, mub.w};
        const float lp[8] = {pia.x, pia.y, pia.z, pia.w, pib.x, pib.y, pib.z, pib.w};
#pragma unroll
        for (int i = 0; i < 4; ++i) {
            mp2[i] = (v2f){-2.0f * C1 * m[2 * i], -2.0f * C1 * m[2 * i + 1]};
            mq2[i] = (v2f){fmaf(C1 * m[2 * i], m[2 * i], C2),
                           fmaf(C1 * m[2 * i + 1], m[2 * i + 1], C2)};
            lp2[i] = (t0 == 0) ? (v2f){lp[2 * i] * LOG2E, lp[2 * i + 1] * LOG2E}
                               : (v2f){0.0f, 0.0f};
        }
    }

    v2f a2[4], e2[4];          // alpha and current-step emissions
    float Z;
    v2f c9v, kzv;
    float acc2 = 0.0f;         // accumulated log2 of normalization scales
    v2f osq2 = (v2f){0.0f, 0.0f};

    auto stepf = [&](float on, bool renorm) {
#pragma unroll
        for (int i = 0; i < 4; ++i) {
            v2f w = fma2(a2[i], c9v, kzv);
            a2[i] = e2[i] * w;
        }
        v2f s0 = a2[0] + a2[1];
        v2f s1 = a2[2] + a2[3];
        v2f ss = s0 + s1;
        float l = ss[0] + ss[1];
        const v2f o2 = (v2f){on, on};
        v2f q0 = fma2(mp2[0], o2, mq2[0]);
        v2f q1 = fma2(mp2[1], o2, mq2[1]);
        l = dpp_add<0x111>(l);                       // row_shr:1
        v2f q2 = fma2(mp2[2], o2, mq2[2]);
        v2f q3 = fma2(mp2[3], o2, mq2[3]);
        l = dpp_add<0x112>(l);                       // row_shr:2
        float e0 = __builtin_amdgcn_exp2f(q0[0]);
        float e1 = __builtin_amdgcn_exp2f(q0[1]);
        l = dpp_add<0x114>(l);                       // row_shr:4
        float e2s = __builtin_amdgcn_exp2f(q1[0]);
        float e3 = __builtin_amdgcn_exp2f(q1[1]);
        l = dpp_add<0x118>(l);                       // row_shr:8
        float e4 = __builtin_amdgcn_exp2f(q2[0]);
        float e5 = __builtin_amdgcn_exp2f(q2[1]);
        l = dpp_add<0x142>(l);                       // row_bcast:15
        float e6 = __builtin_amdgcn_exp2f(q3[0]);
        float e7 = __builtin_amdgcn_exp2f(q3[1]);
        l = dpp_add<0x143>(l);                       // row_bcast:31
        Z = rl63(l);
        if (renorm) {
            acc2 += __builtin_amdgcn_logf(Z);          // log2(Z)
            const float r = __builtin_amdgcn_rcpf(Z);
            const float cc = 0.9f * r;
            c9v = (v2f){cc, cc};
            kzv = (v2f){KE, KE};
        } else {
            const float kz = KE * Z;
            c9v = (v2f){0.9f, 0.9f};
            kzv = (v2f){kz, kz};
        }
        e2[0] = (v2f){e0, e1}; e2[1] = (v2f){e2s, e3};
        e2[2] = (v2f){e4, e5}; e2[3] = (v2f){e6, e7};
    };

    float oc[8], nx[8];
#pragma unroll
    for (int j = 0; j < 8; ++j) oc[j] = s_obs[j];
#pragma unroll
    for (int j = 0; j < 8; ++j) nx[j] = s_obs[8 + j];

    {   // group 0: init at local step 0 (pi if t0==0, uniform otherwise)
        const v2f o0 = (v2f){oc[0], oc[0]};
#pragma unroll
        for (int i = 0; i < 4; ++i) {
            v2f q = fma2(mp2[i], o0, mq2[i]) + lp2[i];
            a2[i] = (v2f){__builtin_amdgcn_exp2f(q[0]), __builtin_amdgcn_exp2f(q[1])};
        }
        v2f ss = (a2[0] + a2[1]) + (a2[2] + a2[3]);
        float l = ss[0] + ss[1];
        l = dpp_add<0x111>(l); l = dpp_add<0x112>(l); l = dpp_add<0x114>(l);
        l = dpp_add<0x118>(l); l = dpp_add<0x142>(l); l = dpp_add<0x143>(l);
        Z = rl63(l);
        const float kz = KE * Z;
        c9v = (v2f){0.9f, 0.9f};
        kzv = (v2f){kz, kz};
        const v2f o1 = (v2f){oc[1], oc[1]};      // emissions for local step 1
#pragma unroll
        for (int i = 0; i < 4; ++i) {
            v2f q = fma2(mp2[i], o1, mq2[i]);
            e2[i] = (v2f){__builtin_amdgcn_exp2f(q[0]), __builtin_amdgcn_exp2f(q[1])};
        }
    }
#pragma unroll
    for (int j = 0; j < 8; j += 2)       // osq over group 0 (kept only if g_reset==0)
        osq2 = fma2((v2f){oc[j], oc[j + 1]}, (v2f){oc[j], oc[j + 1]}, osq2);

    // group 0 steps 1..7 (renorm at local 7)
#pragma unroll
    for (int j = 1; j < 7; ++j) stepf(oc[j + 1], false);
    stepf(nx[0], true);
#pragma unroll
    for (int j = 0; j < 8; ++j) oc[j] = nx[j];

    // groups g = 1..ng-1; accumulators reset entering group g_reset (work start)
#pragma unroll 1
    for (int g = 1; g < ng; ++g) {
        const float4 n0 = *reinterpret_cast<const float4*>(&s_obs[8 * g + 8]);
        const float4 n1 = *reinterpret_cast<const float4*>(&s_obs[8 * g + 12]);
        if (g == g_reset) {               // discard burn-in lnZ and osq
            acc2 = 0.0f;
            osq2 = (v2f){0.0f, 0.0f};
        }
#pragma unroll
        for (int j = 0; j < 8; j += 2)
            osq2 = fma2((v2f){oc[j], oc[j + 1]}, (v2f){oc[j], oc[j + 1]}, osq2);
#pragma unroll
        for (int j = 0; j < 7; ++j) stepf(oc[j + 1], false);
        stepf(n0.x, true);
        oc[0] = n0.x; oc[1] = n0.y; oc[2] = n0.z; oc[3] = n0.w;
        oc[4] = n1.x; oc[5] = n1.y; oc[6] = n1.z; oc[7] = n1.w;
    }

    if (lane == 0)
        part[bid] = LN2 * (acc2 + C1 * (osq2[0] + osq2[1]));
}

// Deterministic tree-reduce of the NBLK partials; plain store to out[0].
__global__ __launch_bounds__(64) void hmm_reduce_kernel(const float* __restrict__ part,
                                                        float* __restrict__ out)
{
    const int lane = threadIdx.x;
    float s = 0.0f;
#pragma unroll
    for (int k = 0; k < NBLK / 64 / 4; ++k) {        // float4 strided over one wave
        const float4 v = reinterpret_cast<const float4*>(part)[lane + 64 * k];
        s += (v.x + v.y) + (v.z + v.w);
    }
    s = dpp_add<0x111>(s); s = dpp_add<0x112>(s); s = dpp_add<0x114>(s);
    s = dpp_add<0x118>(s); s = dpp_add<0x142>(s); s = dpp_add<0x143>(s);
    const float tot = rl63(s);
    if (lane == 0) out[0] = tot;
}

extern "C" void kernel_launch(void* const* d_in, const int* in_sizes, int n_in,
                              void* d_out, int out_size, void* d_ws, size_t ws_size,
                              hipStream_t stream)
{
    const float* obvs  = (const float*)d_in[0];
    const float* mu    = (const float*)d_in[1];
    const float* ln_pi = (const float*)d_in[2];
    float* out  = (float*)d_out;
    float* part = (float*)d_ws;

    hmm_fwd_kernel<<<NBLK, 64, 0, stream>>>(obvs, mu, ln_pi, part);
    hmm_reduce_kernel<<<1, 64, 0, stream>>>(part, out);
}